// Round 5
// baseline (911.787 us; speedup 1.0000x reference)
//
#include <hip/hip_runtime.h>
#include <hip/hip_bf16.h>

#define IN_DIM 256
#define HID    128
#define NSEG   320
#define MAXNORM 0.99999

typedef short bf16x8 __attribute__((ext_vector_type(8)));
typedef float f32x4  __attribute__((ext_vector_type(4)));

static __device__ __forceinline__ ushort f2b(float f) {
    uint u = __builtin_bit_cast(uint, f);
    uint r = 0x7FFFu + ((u >> 16) & 1u);      // round-to-nearest-even
    return (ushort)((u + r) >> 16);
}
static __device__ __forceinline__ float b2f_lo(uint v) {
    return __builtin_bit_cast(float, v << 16);
}
static __device__ __forceinline__ float b2f_hi(uint v) {
    return __builtin_bit_cast(float, v & 0xFFFF0000u);
}

// ---------------------------------------------------------------------------
// CSR build: count -> exclusive scan -> fill (per-dst-node, reused twice)
// ---------------------------------------------------------------------------
__global__ void count_edges_k(const int* __restrict__ dst, int* __restrict__ counts, int n) {
    int e = blockIdx.x * 256 + threadIdx.x;
    if (e < n) atomicAdd(&counts[dst[e]], 1);
}

__global__ void scan_block_k(const int* __restrict__ in, int* __restrict__ out,
                             int* __restrict__ partials) {
    __shared__ int sh[256];
    int tid = threadIdx.x;
    int base = blockIdx.x * 1024 + tid * 4;
    int4 v = *(const int4*)&in[base];
    int s = v.x + v.y + v.z + v.w;
    sh[tid] = s;
    __syncthreads();
#pragma unroll
    for (int off = 1; off < 256; off <<= 1) {
        int t = (tid >= off) ? sh[tid - off] : 0;
        __syncthreads();
        sh[tid] += t;
        __syncthreads();
    }
    int excl = sh[tid] - s;
    int4 o;
    o.x = excl; o.y = excl + v.x; o.z = o.y + v.y; o.w = o.z + v.z;
    *(int4*)&out[base] = o;
    if (tid == 255) partials[blockIdx.x] = sh[255];
}

__global__ void scan_partials_k(int* __restrict__ partials, int n) {
    __shared__ int sh[1024];
    int tid = threadIdx.x;
    int v = (tid < n) ? partials[tid] : 0;
    sh[tid] = v;
    __syncthreads();
    for (int off = 1; off < blockDim.x; off <<= 1) {
        int t = (tid >= off) ? sh[tid - off] : 0;
        __syncthreads();
        sh[tid] += t;
        __syncthreads();
    }
    if (tid < n) partials[tid] = sh[tid] - v;
}

__global__ void add_base_k(int* __restrict__ offsets, const int* __restrict__ partials, int n) {
    int g = blockIdx.x * 256 + threadIdx.x;
    if (g < n) offsets[g] += partials[g >> 10];
}

__global__ void fill_edges_k(const int* __restrict__ src, const int* __restrict__ dst,
                             const int* __restrict__ offsets, int* __restrict__ cursor,
                             int* __restrict__ sorted_src, int n) {
    int e = blockIdx.x * 256 + threadIdx.x;
    if (e < n) {
        int d = dst[e];
        int pos = atomicAdd(&cursor[d], 1);
        sorted_src[offsets[d] + pos] = src[e];
    }
}

// ---------------------------------------------------------------------------
// W pre-transpose+convert: W[K][128] f32 -> WT[128][K] bf16 (both weights)
// ---------------------------------------------------------------------------
__global__ void prep_wt_k(const float* __restrict__ w1, const float* __restrict__ w2,
                          ushort* __restrict__ w1t, ushort* __restrict__ w2t) {
    int id = blockIdx.x * 256 + threadIdx.x;
    if (id < 32768) {                      // W1: 256x128 -> 128x256
        int n = id >> 8, k = id & 255;
        w1t[n * 256 + k] = f2b(w1[k * 128 + n]);
    } else {                               // W2: 128x128 -> 128x128
        int id2 = id - 32768;
        int n = id2 >> 7, k = id2 & 127;
        w2t[n * 128 + k] = f2b(w2[k * 128 + n]);
    }
}

// ---------------------------------------------------------------------------
// bf16 MFMA GEMM: C[M][128](bf16) = A[M][K] @ B[K][128]   (unchanged, verified)
// ---------------------------------------------------------------------------
template<bool AF32>
__global__ __launch_bounds__(256) void gemm_k(const void* __restrict__ Ap,
                                              const ushort* __restrict__ BT,
                                              ushort* __restrict__ C, int K) {
    __shared__ __align__(16) char As[16384];   // [128][64] bf16, swizzled
    __shared__ __align__(16) char Bs[16384];   // [128(n)][64(k)] bf16, swizzled
    const int tid = threadIdx.x;
    const int lane = tid & 63;
    const int wid = tid >> 6;
    const int wr = wid >> 1, wc = wid & 1;
    const int row0 = blockIdx.x * 128;
    f32x4 acc[4][4] = {};

    for (int k0 = 0; k0 < K; k0 += 64) {
        if (AF32) {
            const float* A = (const float*)Ap;
#pragma unroll
            for (int it = 0; it < 8; ++it) {
                int id = tid + it * 256;
                int r = id >> 4, c4 = (id & 15) * 4;
                float4 v = *(const float4*)&A[(size_t)(row0 + r) * K + k0 + c4];
                ushort4 h;
                h.x = f2b(v.x); h.y = f2b(v.y); h.z = f2b(v.z); h.w = f2b(v.w);
                *(ushort4*)(As + ((r * 128 + c4 * 2) ^ ((r & 7) << 4))) = h;
            }
        } else {
            const ushort* A = (const ushort*)Ap;
#pragma unroll
            for (int it = 0; it < 4; ++it) {
                int id = tid + it * 256;
                int r = id >> 3, c8 = (id & 7) * 8;
                bf16x8 v = *(const bf16x8*)&A[(size_t)(row0 + r) * K + k0 + c8];
                *(bf16x8*)(As + ((r * 128 + c8 * 2) ^ ((r & 7) << 4))) = v;
            }
        }
#pragma unroll
        for (int it = 0; it < 4; ++it) {
            int id = tid + it * 256;
            int n = id >> 3, c8 = (id & 7) * 8;
            bf16x8 v = *(const bf16x8*)&BT[(size_t)n * K + k0 + c8];
            *(bf16x8*)(Bs + ((n * 128 + c8 * 2) ^ ((n & 7) << 4))) = v;
        }
        __syncthreads();
#pragma unroll
        for (int kc = 0; kc < 2; ++kc) {
            bf16x8 af[4], bfr[4];
            int kb = (kc * 32 + (lane >> 4) * 8) * 2;
#pragma unroll
            for (int i = 0; i < 4; ++i) {
                int r = wr * 64 + i * 16 + (lane & 15);
                af[i] = *(const bf16x8*)(As + ((r * 128 + kb) ^ ((r & 7) << 4)));
                int n = wc * 64 + i * 16 + (lane & 15);
                bfr[i] = *(const bf16x8*)(Bs + ((n * 128 + kb) ^ ((n & 7) << 4)));
            }
#pragma unroll
            for (int i = 0; i < 4; ++i)
#pragma unroll
                for (int j = 0; j < 4; ++j)
                    acc[i][j] = __builtin_amdgcn_mfma_f32_16x16x32_bf16(
                        af[i], bfr[j], acc[i][j], 0, 0, 0);
        }
        __syncthreads();
    }
#pragma unroll
    for (int i = 0; i < 4; ++i)
#pragma unroll
        for (int j = 0; j < 4; ++j)
#pragma unroll
            for (int r = 0; r < 4; ++r) {
                int row = row0 + wr * 64 + i * 16 + (lane >> 4) * 4 + r;
                int col = wc * 64 + j * 16 + (lane & 15);
                C[(size_t)row * 128 + col] = f2b(acc[i][j][r]);
            }
}

// ---------------------------------------------------------------------------
// x4-packed gather: wave per node; quadrant q=lane>>4 owns edge j+4u+q,
// lane c=lane&15 loads dwordx4 (8 dims) -> ONE instruction fetches 4 full
// 256B rows. 4 loads per 16 edges (vs 16). Quadrant partials reduced by
// shfl_xor(16/32) at the end.
// ---------------------------------------------------------------------------
#define ACC8(vv)                                                       \
    do { acc[0] += b2f_lo((vv).x); acc[1] += b2f_hi((vv).x);           \
         acc[2] += b2f_lo((vv).y); acc[3] += b2f_hi((vv).y);           \
         acc[4] += b2f_lo((vv).z); acc[5] += b2f_hi((vv).z);           \
         acc[6] += b2f_lo((vv).w); acc[7] += b2f_hi((vv).w); } while (0)

template<bool POOL>
__global__ __launch_bounds__(256) void gather_x4_k(
    const ushort* __restrict__ sup, const int* __restrict__ offsets,
    const int* __restrict__ counts, const int* __restrict__ ssrc,
    const float* __restrict__ bias, const int* __restrict__ seg_ids,
    uint* __restrict__ h1, float* __restrict__ sums, int* __restrict__ seg_cnt,
    int n_nodes) {
    const int node = (blockIdx.x << 2) | (threadIdx.x >> 6);
    const int lane = threadIdx.x & 63;
    const int q = lane >> 4, c = lane & 15;
    const int off = offsets[node];
    const int cnt = counts[node];
    const int n0 = min(cnt, 64);
    float acc[8] = {};
    int my = 0;
    if (lane < n0) my = ssrc[off + lane];

    int j = 0;
    for (; j + 16 <= n0; j += 16) {
        uint4 v[4];
#pragma unroll
        for (int u = 0; u < 4; ++u) {
            int r = __shfl(my, j + u * 4 + q);
            v[u] = *(const uint4*)&sup[(size_t)r * 128 + c * 8];
        }
#pragma unroll
        for (int u = 0; u < 4; ++u) ACC8(v[u]);
    }
    if (j < n0) {
#pragma unroll
        for (int u = 0; u < 4; ++u) {
            int e = j + u * 4 + q;
            int r = __shfl(my, e);          // exec-uniform shfl
            if (e < n0) {
                uint4 v = *(const uint4*)&sup[(size_t)r * 128 + c * 8];
                ACC8(v);
            }
        }
    }
    for (int e = 64; e < cnt; ++e) {        // Poisson(16) tail: ~never
        if (q == 0) {
            int r = ssrc[off + e];
            uint4 v = *(const uint4*)&sup[(size_t)r * 128 + c * 8];
            ACC8(v);
        }
    }
    // reduce quadrant partials: dims c*8..c*8+7 summed across q
#pragma unroll
    for (int i = 0; i < 8; ++i) {
        acc[i] += __shfl_xor(acc[i], 16);
        acc[i] += __shfl_xor(acc[i], 32);
    }
    float4 b0 = *(const float4*)&bias[c * 8];
    float4 b1 = *(const float4*)&bias[c * 8 + 4];
    float h[8];
    h[0] = tanhf(acc[0] + b0.x); h[1] = tanhf(acc[1] + b0.y);
    h[2] = tanhf(acc[2] + b0.z); h[3] = tanhf(acc[3] + b0.w);
    h[4] = tanhf(acc[4] + b1.x); h[5] = tanhf(acc[5] + b1.y);
    h[6] = tanhf(acc[6] + b1.z); h[7] = tanhf(acc[7] + b1.w);

    if (!POOL) {
        if (q == 0) {
            uint4 o;
            o.x = ((uint)f2b(h[1]) << 16) | (uint)f2b(h[0]);
            o.y = ((uint)f2b(h[3]) << 16) | (uint)f2b(h[2]);
            o.z = ((uint)f2b(h[5]) << 16) | (uint)f2b(h[4]);
            o.w = ((uint)f2b(h[7]) << 16) | (uint)f2b(h[6]);
            *(uint4*)&h1[(size_t)node * 64 + c * 4] = o;
        }
    } else {
        float ss = h[0]*h[0] + h[1]*h[1] + h[2]*h[2] + h[3]*h[3]
                 + h[4]*h[4] + h[5]*h[5] + h[6]*h[6] + h[7]*h[7];
#pragma unroll
        for (int o2 = 1; o2 <= 8; o2 <<= 1) ss += __shfl_xor(ss, o2);
        // each 16-lane quadrant holds all 128 dims -> ss is the full norm^2
        double rr = sqrt((double)fmaxf(ss, 1e-15f));
        double m = fmin(rr, MAXNORM);
        float f = (float)(atanh(m) / rr);       // logmap0(proj(h)) scale
        if (q == 0) {
            int seg = seg_ids[node];
#pragma unroll
            for (int i = 0; i < 8; ++i)
                atomicAdd(&sums[seg * 128 + c * 8 + i], h[i] * f);
            if (lane == 0) atomicAdd(&seg_cnt[seg], 1);
        }
    }
}

// segment mean -> expmap0 -> proj
__global__ __launch_bounds__(64) void finalize_k(const float* __restrict__ sums,
                                                 const int* __restrict__ seg_cnt,
                                                 float* __restrict__ out) {
    int seg = blockIdx.x;
    int lane = threadIdx.x;
    float c = fmaxf((float)seg_cnt[seg], 1.0f);
    float ux = sums[seg * 128 + 2 * lane] / c;
    float uy = sums[seg * 128 + 2 * lane + 1] / c;
    float ss = ux * ux + uy * uy;
#pragma unroll
    for (int o = 32; o > 0; o >>= 1) ss += __shfl_xor(ss, o);
    double r = sqrt((double)fmaxf(ss, 1e-15f));
    double t = tanh(r);
    double fac = t / r;
    if (t > MAXNORM) fac = MAXNORM / r;
    float f = (float)fac;
    out[seg * 128 + 2 * lane] = ux * f;
    out[seg * 128 + 2 * lane + 1] = uy * f;
}

// ---------------------------------------------------------------------------
extern "C" void kernel_launch(void* const* d_in, const int* in_sizes, int n_in,
                              void* d_out, int out_size, void* d_ws, size_t ws_size,
                              hipStream_t stream) {
    const float* x   = (const float*)d_in[0];
    const int* src   = (const int*)d_in[1];
    const int* dst   = (const int*)d_in[2];
    const int* segid = (const int*)d_in[3];
    const float* W1  = (const float*)d_in[4];
    const float* b1  = (const float*)d_in[5];
    const float* W2  = (const float*)d_in[6];
    const float* b2  = (const float*)d_in[7];
    float* out       = (float*)d_out;

    const int N = in_sizes[3];          // 131072
    const int E = in_sizes[1];          // 2097152

    char* ws = (char*)d_ws;
    ushort* supA   = (ushort*)(ws);                      // N*128 bf16 = 32MB
    uint*   h1u    = (uint*)(ws + 33554432);             // N*128 bf16 = 32MB
    ushort* h1     = (ushort*)h1u;
    int* ssrc      = (int*)(ws + 67108864);              // E ints = 8MB
    int* counts    = (int*)(ws + 75497472);
    int* offsets   = (int*)(ws + 76021760);
    int* cursor    = (int*)(ws + 76546048);
    int* partials  = (int*)(ws + 77070336);
    float* sums    = (float*)(ws + 77071360);
    int* seg_cnt   = (int*)(ws + 77235200);
    ushort* w1t    = (ushort*)(ws + 77236480);           // 128x256 bf16
    ushort* w2t    = (ushort*)(ws + 77302016);           // 128x128 bf16

    hipMemsetAsync(counts, 0, (size_t)N * 4, stream);
    hipMemsetAsync(cursor, 0, (size_t)N * 4, stream);
    hipMemsetAsync(sums, 0, (size_t)NSEG * 128 * 4, stream);
    hipMemsetAsync(seg_cnt, 0, (size_t)NSEG * 4, stream);

    const int eblocks = (E + 255) / 256;
    const int nscan = N / 1024;

    prep_wt_k<<<192, 256, 0, stream>>>(W1, W2, w1t, w2t);

    count_edges_k<<<eblocks, 256, 0, stream>>>(dst, counts, E);
    scan_block_k<<<nscan, 256, 0, stream>>>(counts, offsets, partials);
    scan_partials_k<<<1, nscan, 0, stream>>>(partials, nscan);
    add_base_k<<<(N + 255) / 256, 256, 0, stream>>>(offsets, partials, N);
    fill_edges_k<<<eblocks, 256, 0, stream>>>(src, dst, offsets, cursor, ssrc, E);

    // layer 1
    gemm_k<true><<<N / 128, 256, 0, stream>>>(x, w1t, supA, IN_DIM);
    gather_x4_k<false><<<N / 4, 256, 0, stream>>>(supA, offsets, counts, ssrc, b1,
                                                  segid, h1u, sums, seg_cnt, N);

    // layer 2
    gemm_k<false><<<N / 128, 256, 0, stream>>>(h1, w2t, supA, HID);
    gather_x4_k<true><<<N / 4, 256, 0, stream>>>(supA, offsets, counts, ssrc, b2,
                                                 segid, h1u, sums, seg_cnt, N);

    finalize_k<<<NSEG, 64, 0, stream>>>(sums, seg_cnt, out);
}

// Round 7
// 792.262 us; speedup vs baseline: 1.1509x; 1.1509x over previous
//
#include <hip/hip_runtime.h>
#include <hip/hip_bf16.h>

#define IN_DIM 256
#define HID    128
#define NSEG   320
#define MAXNORM 0.99999

#define NPAN   8                     // panels per 16MB half-buffer (2MB each)
#define PANSH  14                    // src>>14 -> 16384 rows/panel
#define NWAVE  4096                  // 131072/32 dst nodes per wave
#define NKEY   (NWAVE * 256)         // (dst>>5)*256 + panel*32 + (dst&31) = 1M

typedef short bf16x8 __attribute__((ext_vector_type(8)));
typedef float f32x4  __attribute__((ext_vector_type(4)));

static __device__ __forceinline__ ushort f2b(float f) {
    uint u = __builtin_bit_cast(uint, f);
    uint r = 0x7FFFu + ((u >> 16) & 1u);      // round-to-nearest-even
    return (ushort)((u + r) >> 16);
}
static __device__ __forceinline__ float b2f_lo(uint v) {
    return __builtin_bit_cast(float, v << 16);
}
static __device__ __forceinline__ float b2f_hi(uint v) {
    return __builtin_bit_cast(float, v & 0xFFFF0000u);
}
static __device__ __forceinline__ float b2fu(ushort u) {
    return __builtin_bit_cast(float, (uint)u << 16);
}

// ---------------------------------------------------------------------------
// Edge sort: key = (dst>>5)*256 + (src>>PANSH)*32 + (dst&31)
// ---------------------------------------------------------------------------
__global__ void count_edges_k(const int* __restrict__ src, const int* __restrict__ dst,
                              int* __restrict__ counts, int n) {
    int e = blockIdx.x * 256 + threadIdx.x;
    if (e < n) {
        int d = dst[e];
        int key = ((d >> 5) << 8) | ((src[e] >> PANSH) << 5) | (d & 31);
        atomicAdd(&counts[key], 1);
    }
}

__global__ void scan_block_k(const int* __restrict__ in, int* __restrict__ out,
                             int* __restrict__ partials) {
    __shared__ int sh[256];
    int tid = threadIdx.x;
    int base = blockIdx.x * 1024 + tid * 4;
    int4 v = *(const int4*)&in[base];
    int s = v.x + v.y + v.z + v.w;
    sh[tid] = s;
    __syncthreads();
#pragma unroll
    for (int off = 1; off < 256; off <<= 1) {
        int t = (tid >= off) ? sh[tid - off] : 0;
        __syncthreads();
        sh[tid] += t;
        __syncthreads();
    }
    int excl = sh[tid] - s;
    int4 o;
    o.x = excl; o.y = excl + v.x; o.z = o.y + v.y; o.w = o.z + v.z;
    *(int4*)&out[base] = o;
    if (tid == 255) partials[blockIdx.x] = sh[255];
}

__global__ void scan_partials_k(int* __restrict__ partials, int n) {
    __shared__ int sh[1024];
    int tid = threadIdx.x;
    int v = (tid < n) ? partials[tid] : 0;
    sh[tid] = v;
    __syncthreads();
    for (int off = 1; off < blockDim.x; off <<= 1) {
        int t = (tid >= off) ? sh[tid - off] : 0;
        __syncthreads();
        sh[tid] += t;
        __syncthreads();
    }
    if (tid < n) partials[tid] = sh[tid] - v;
}

__global__ void add_base_k(int* __restrict__ offsets, const int* __restrict__ partials, int n) {
    int g = blockIdx.x * 256 + threadIdx.x;
    if (g < n) offsets[g] += partials[g >> 10];
}

// packed edge = src | ((dst&31)<<20)
__global__ void fill_edges_k(const int* __restrict__ src, const int* __restrict__ dst,
                             const int* __restrict__ offsets, int* __restrict__ cursor,
                             uint* __restrict__ packed, int n) {
    int e = blockIdx.x * 256 + threadIdx.x;
    if (e < n) {
        int s = src[e], d = dst[e];
        int key = ((d >> 5) << 8) | ((s >> PANSH) << 5) | (d & 31);
        int pos = atomicAdd(&cursor[key], 1);
        packed[offsets[key] + pos] = (uint)s | ((uint)(d & 31) << 20);
    }
}

// goff2[w*8+p] = start of (wave w, panel p) bucket; goff2[NWAVE*8] = E
__global__ void extract_goff2_k(const int* __restrict__ offsets, int* __restrict__ goff2, int E) {
    int i = blockIdx.x * 256 + threadIdx.x;
    if (i < NWAVE * NPAN) goff2[i] = offsets[(i >> 3) * 256 + (i & 7) * 32];
    if (i == NWAVE * NPAN) goff2[i] = E;
}

// ---------------------------------------------------------------------------
// W pre-transpose+convert: W[K][128] f32 -> WT[128][K] bf16 (both weights)
// ---------------------------------------------------------------------------
__global__ void prep_wt_k(const float* __restrict__ w1, const float* __restrict__ w2,
                          ushort* __restrict__ w1t, ushort* __restrict__ w2t) {
    int id = blockIdx.x * 256 + threadIdx.x;
    if (id < 32768) {
        int n = id >> 8, k = id & 255;
        w1t[n * 256 + k] = f2b(w1[k * 128 + n]);
    } else {
        int id2 = id - 32768;
        int n = id2 >> 7, k = id2 & 127;
        w2t[n * 128 + k] = f2b(w2[k * 128 + n]);
    }
}

// ---------------------------------------------------------------------------
// bf16 MFMA GEMM: C = A @ B, output split into CLo (cols 0-63) / CHi (64-127)
// ---------------------------------------------------------------------------
template<bool AF32>
__global__ __launch_bounds__(256) void gemm_k(const void* __restrict__ Ap,
                                              const ushort* __restrict__ BT,
                                              ushort* __restrict__ CLo,
                                              ushort* __restrict__ CHi, int K) {
    __shared__ __align__(16) char As[16384];   // [128][64] bf16, swizzled
    __shared__ __align__(16) char Bs[16384];
    const int tid = threadIdx.x;
    const int lane = tid & 63;
    const int wid = tid >> 6;
    const int wr = wid >> 1, wc = wid & 1;
    const int row0 = blockIdx.x * 128;
    f32x4 acc[4][4] = {};

    for (int k0 = 0; k0 < K; k0 += 64) {
        if (AF32) {
            const float* A = (const float*)Ap;
#pragma unroll
            for (int it = 0; it < 8; ++it) {
                int id = tid + it * 256;
                int r = id >> 4, c4 = (id & 15) * 4;
                float4 v = *(const float4*)&A[(size_t)(row0 + r) * K + k0 + c4];
                ushort4 h;
                h.x = f2b(v.x); h.y = f2b(v.y); h.z = f2b(v.z); h.w = f2b(v.w);
                *(ushort4*)(As + ((r * 128 + c4 * 2) ^ ((r & 7) << 4))) = h;
            }
        } else {
            const ushort* A = (const ushort*)Ap;
#pragma unroll
            for (int it = 0; it < 4; ++it) {
                int id = tid + it * 256;
                int r = id >> 3, c8 = (id & 7) * 8;
                bf16x8 v = *(const bf16x8*)&A[(size_t)(row0 + r) * K + k0 + c8];
                *(bf16x8*)(As + ((r * 128 + c8 * 2) ^ ((r & 7) << 4))) = v;
            }
        }
#pragma unroll
        for (int it = 0; it < 4; ++it) {
            int id = tid + it * 256;
            int n = id >> 3, c8 = (id & 7) * 8;
            bf16x8 v = *(const bf16x8*)&BT[(size_t)n * K + k0 + c8];
            *(bf16x8*)(Bs + ((n * 128 + c8 * 2) ^ ((n & 7) << 4))) = v;
        }
        __syncthreads();
#pragma unroll
        for (int kc = 0; kc < 2; ++kc) {
            bf16x8 af[4], bfr[4];
            int kb = (kc * 32 + (lane >> 4) * 8) * 2;
#pragma unroll
            for (int i = 0; i < 4; ++i) {
                int r = wr * 64 + i * 16 + (lane & 15);
                af[i] = *(const bf16x8*)(As + ((r * 128 + kb) ^ ((r & 7) << 4)));
                int n = wc * 64 + i * 16 + (lane & 15);
                bfr[i] = *(const bf16x8*)(Bs + ((n * 128 + kb) ^ ((n & 7) << 4)));
            }
#pragma unroll
            for (int i = 0; i < 4; ++i)
#pragma unroll
                for (int j = 0; j < 4; ++j)
                    acc[i][j] = __builtin_amdgcn_mfma_f32_16x16x32_bf16(
                        af[i], bfr[j], acc[i][j], 0, 0, 0);
        }
        __syncthreads();
    }
    ushort* Cb = wc ? CHi : CLo;               // wave-uniform half select
#pragma unroll
    for (int i = 0; i < 4; ++i)
#pragma unroll
        for (int j = 0; j < 4; ++j)
#pragma unroll
            for (int r = 0; r < 4; ++r) {
                int row = row0 + wr * 64 + i * 16 + (lane >> 4) * 4 + r;
                int col = j * 16 + (lane & 15);          // 0..63 within half
                Cb[(size_t)row * 64 + col] = f2b(acc[i][j][r]);
            }
}

// ---------------------------------------------------------------------------
// Phase-coherent gather. 1024 blocks x 4 waves, ALL co-resident (32KB LDS,
// 4 blocks/CU). Wave owns 32 dst nodes; LDS f32 acc [32 nodes][64 dims].
// Two passes (dims 0-63 from supLo, 64-127 from supHi); per pass, 8 panel
// phases: prefetch panel p+1 (streamed, XOR-folded + asm-sunk) while
// consuming panel p (uniform scalar edge indices, 8-deep row loads -> L2).
// ---------------------------------------------------------------------------
__global__ __launch_bounds__(256) void gather_ph_k(
    const ushort* __restrict__ supLo, const ushort* __restrict__ supHi,
    const uint* __restrict__ packed, const int* __restrict__ goff2,
    const float* __restrict__ bias, ushort* __restrict__ hout) {
    __shared__ float accs[4][2048];            // 32KB: [wave][32 nodes * 64]
    const int ws = threadIdx.x >> 6;
    const int lane = threadIdx.x & 63;
    const int w = blockIdx.x * 4 + ws;         // wave id 0..4095
    float* accw = accs[ws];
    const int slice = (blockIdx.x >> 3) & 127; // per-XCD panel slice (heuristic)

    for (int pass = 0; pass < 2; ++pass) {
        const ushort* sup = pass ? supHi : supLo;
        for (int i = lane; i < 2048; i += 64) accw[i] = 0.f;

        uint k0, k1, k2, k3;
        {   // prefetch panel 0
            const uint4* pb = (const uint4*)sup + slice * 1024 + ws * 256 + lane;
            uint4 a = pb[0], b = pb[64], c = pb[128], d = pb[192];
            k0 = a.x ^ a.y ^ a.z ^ a.w; k1 = b.x ^ b.y ^ b.z ^ b.w;
            k2 = c.x ^ c.y ^ c.z ^ c.w; k3 = d.x ^ d.y ^ d.z ^ d.w;
            asm volatile("" :: "v"(k0), "v"(k1), "v"(k2), "v"(k3));
        }
        for (int p = 0; p < NPAN; ++p) {
            if (p < NPAN - 1) {                // stream panel p+1 into L2
                const uint4* pb = (const uint4*)sup + (size_t)(p + 1) * 131072
                                  + slice * 1024 + ws * 256 + lane;
                uint4 a = pb[0], b = pb[64], c = pb[128], d = pb[192];
                k0 = a.x ^ a.y ^ a.z ^ a.w; k1 = b.x ^ b.y ^ b.z ^ b.w;
                k2 = c.x ^ c.y ^ c.z ^ c.w; k3 = d.x ^ d.y ^ d.z ^ d.w;
            }
            int a = __builtin_amdgcn_readfirstlane(goff2[w * NPAN + p]);
            int b = __builtin_amdgcn_readfirstlane(goff2[w * NPAN + p + 1]);
            float accv = 0.f;
            int prev = -1;
            int e = a;
            for (; e + 8 <= b; e += 8) {
                uint pes[8]; ushort vs[8];
#pragma unroll
                for (int t = 0; t < 8; ++t) pes[t] = packed[e + t];   // s_load
#pragma unroll
                for (int t = 0; t < 8; ++t)
                    vs[t] = sup[(size_t)(pes[t] & 0xFFFFFu) * 64 + lane];
#pragma unroll
                for (int t = 0; t < 8; ++t) {
                    int dl = (int)(pes[t] >> 20);
                    if (dl != prev) {
                        if (prev >= 0) accw[prev * 64 + lane] += accv;
                        accv = 0.f; prev = dl;
                    }
                    accv += b2fu(vs[t]);
                }
            }
            for (; e < b; ++e) {
                uint pe = packed[e];
                int dl = (int)(pe >> 20);
                if (dl != prev) {
                    if (prev >= 0) accw[prev * 64 + lane] += accv;
                    accv = 0.f; prev = dl;
                }
                accv += b2fu(sup[(size_t)(pe & 0xFFFFFu) * 64 + lane]);
            }
            if (prev >= 0) accw[prev * 64 + lane] += accv;
            asm volatile("" :: "v"(k0), "v"(k1), "v"(k2), "v"(k3));
        }
        // epilogue: tanh(acc + bias) -> hout dims [pass*64, pass*64+64)
        float bv = bias[pass * 64 + lane];
#pragma unroll 4
        for (int n = 0; n < 32; ++n) {
            int node = w * 32 + n;
            float th = tanhf(accw[n * 64 + lane] + bv);
            hout[(size_t)node * 128 + pass * 64 + lane] = f2b(th);
        }
    }
}

// ---------------------------------------------------------------------------
// Pool pass: stream h2 rows, logmap0(proj(h)) scale, segment-sum atomics
// ---------------------------------------------------------------------------
__global__ __launch_bounds__(256) void pool_k(
    const uint* __restrict__ h2u, const int* __restrict__ seg_ids,
    float* __restrict__ sums, int* __restrict__ seg_cnt, int n_nodes) {
    int node = (blockIdx.x << 2) | (threadIdx.x >> 6);
    if (node >= n_nodes) return;
    int lane = threadIdx.x & 63;
    uint v = h2u[(size_t)node * 64 + lane];
    float hx = b2f_lo(v), hy = b2f_hi(v);
    float ss = hx * hx + hy * hy;
#pragma unroll
    for (int o = 32; o > 0; o >>= 1) ss += __shfl_xor(ss, o);
    double rr = sqrt((double)fmaxf(ss, 1e-15f));
    double m = fmin(rr, MAXNORM);
    float f = (float)(atanh(m) / rr);
    int seg = seg_ids[node];
    atomicAdd(&sums[seg * 128 + 2 * lane], hx * f);
    atomicAdd(&sums[seg * 128 + 2 * lane + 1], hy * f);
    if (lane == 0) atomicAdd(&seg_cnt[seg], 1);
}

// segment mean -> expmap0 -> proj
__global__ __launch_bounds__(64) void finalize_k(const float* __restrict__ sums,
                                                 const int* __restrict__ seg_cnt,
                                                 float* __restrict__ out) {
    int seg = blockIdx.x;
    int lane = threadIdx.x;
    float c = fmaxf((float)seg_cnt[seg], 1.0f);
    float ux = sums[seg * 128 + 2 * lane] / c;
    float uy = sums[seg * 128 + 2 * lane + 1] / c;
    float ss = ux * ux + uy * uy;
#pragma unroll
    for (int o = 32; o > 0; o >>= 1) ss += __shfl_xor(ss, o);
    double r = sqrt((double)fmaxf(ss, 1e-15f));
    double t = tanh(r);
    double fac = t / r;
    if (t > MAXNORM) fac = MAXNORM / r;
    float f = (float)fac;
    out[seg * 128 + 2 * lane] = ux * f;
    out[seg * 128 + 2 * lane + 1] = uy * f;
}

// ---------------------------------------------------------------------------
extern "C" void kernel_launch(void* const* d_in, const int* in_sizes, int n_in,
                              void* d_out, int out_size, void* d_ws, size_t ws_size,
                              hipStream_t stream) {
    const float* x   = (const float*)d_in[0];
    const int* src   = (const int*)d_in[1];
    const int* dst   = (const int*)d_in[2];
    const int* segid = (const int*)d_in[3];
    const float* W1  = (const float*)d_in[4];
    const float* b1  = (const float*)d_in[5];
    const float* W2  = (const float*)d_in[6];
    const float* b2  = (const float*)d_in[7];
    float* out       = (float*)d_out;

    const int N = in_sizes[3];          // 131072
    const int E = in_sizes[1];          // 2097152

    char* ws = (char*)d_ws;
    // persistent
    ushort* supLo  = (ushort*)(ws);                      // 16MB [N][64] bf16
    ushort* supHi  = (ushort*)(ws + 16777216);           // 16MB
    ushort* h1     = (ushort*)(ws + 33554432);           // 32MB [N][128] bf16
    ushort* h2     = (ushort*)(ws + 67108864);           // 32MB
    uint*   h2u    = (uint*)h2;
    uint* packed   = (uint*)(ws + 100663296);            // 8MB
    int* goff2     = (int*)(ws + 109051904);             // 128KB+
    float* sums    = (float*)(ws + 110100480);           // 160KB
    int* seg_cnt   = (int*)(ws + 110264320);
    ushort* w1t    = (ushort*)(ws + 110265600);          // 64KB
    ushort* w2t    = (ushort*)(ws + 110331136);          // 32KB
    // sort scratch aliased into h1/h2 regions (dead before their writers)
    int* counts    = (int*)(ws + 33554432);              // 4MB
    int* offsets   = (int*)(ws + 37748736);              // 4MB
    int* cursor    = (int*)(ws + 41943040);              // 4MB
    int* partials  = (int*)(ws + 67108864);              // 4KB (in h2 region)

    hipMemsetAsync(counts, 0, (size_t)NKEY * 4, stream);
    hipMemsetAsync(cursor, 0, (size_t)NKEY * 4, stream);
    hipMemsetAsync(sums, 0, (size_t)NSEG * 128 * 4, stream);
    hipMemsetAsync(seg_cnt, 0, (size_t)NSEG * 4, stream);

    const int eblocks = (E + 255) / 256;

    prep_wt_k<<<192, 256, 0, stream>>>(W1, W2, w1t, w2t);

    // edge sort by (dst-wave, src-panel, dst-local)
    count_edges_k<<<eblocks, 256, 0, stream>>>(src, dst, counts, E);
    scan_block_k<<<NKEY / 1024, 256, 0, stream>>>(counts, offsets, partials);
    scan_partials_k<<<1, 1024, 0, stream>>>(partials, NKEY / 1024);
    add_base_k<<<NKEY / 256, 256, 0, stream>>>(offsets, partials, NKEY);
    fill_edges_k<<<eblocks, 256, 0, stream>>>(src, dst, offsets, cursor, packed, E);
    extract_goff2_k<<<(NWAVE * NPAN + 256) / 256, 256, 0, stream>>>(offsets, goff2, E);

    // layer 1
    gemm_k<true><<<N / 128, 256, 0, stream>>>(x, w1t, supLo, supHi, IN_DIM);
    gather_ph_k<<<1024, 256, 0, stream>>>(supLo, supHi, packed, goff2, b1, h1);

    // layer 2
    gemm_k<false><<<N / 128, 256, 0, stream>>>(h1, w2t, supLo, supHi, HID);
    gather_ph_k<<<1024, 256, 0, stream>>>(supLo, supHi, packed, goff2, b2, h2);

    // pool + finalize
    pool_k<<<N / 4, 256, 0, stream>>>(h2u, segid, sums, seg_cnt, N);
    finalize_k<<<NSEG, 64, 0, stream>>>(sums, seg_cnt, out);
}